// Round 5
// baseline (192.090 us; speedup 1.0000x reference)
//
#include <hip/hip_runtime.h>

// CTC loss forward DP (Keras ctc_batch_cost), mean over batch.
// B=512, T=512, C=96 (blank=95), L=64. One wave per example; lane i owns
// extended states 2i (blank) and 2i+1 (label i); lane 63 also owns state 128.
//
// R5: memory path restructured. Old: per-lane label gathers (64-lane scatter
// over a 384B row -> ~6 L1-missing lines per inst, ~3600 line-fills/wave =
// the ~48us limiter). New: 8-row chunks (3KB) fetched with 3 fully-coalesced
// dwordx4 loads into a depth-4 VGPR ring, staged to a 2-slot LDS buffer
// (1 wave/block -> zero barriers), consumed via ds_read_b32 off two hoisted
// vaddrs (label: lab*4 per lane; blank: uniform broadcast). DP itself
// unchanged from R4 (linear space, post-chunk renorm to 2^96, FMA step).
// Chunk-0 special case removed via virtual t=-1 init (alpha[-1][0] = 2^96).

#define B_ 512
#define T_ 512
#define C_ 96
#define L_ 64
#define BLANK_ 95
#define EPSF 1e-7f
#define LN2F 0.69314718055994530942f

template <int CTRL>
__device__ __forceinline__ float dpp_mov(float x) {
    // bound_ctrl=true: invalid source lanes read 0 (identity for max of
    // non-negative probs; exactly the "state -1 absent" boundary for shr:1).
    return __int_as_float(
        __builtin_amdgcn_update_dpp(0, __float_as_int(x), CTRL, 0xF, 0xF, true));
}

// Full-wave max (64 lanes), all-VALU; full reduction lands in lane 63.
__device__ __forceinline__ float wave_max(float m) {
    m = fmaxf(m, dpp_mov<0x111>(m));  // row_shr:1
    m = fmaxf(m, dpp_mov<0x112>(m));  // row_shr:2
    m = fmaxf(m, dpp_mov<0x114>(m));  // row_shr:4
    m = fmaxf(m, dpp_mov<0x118>(m));  // row_shr:8
    m = fmaxf(m, dpp_mov<0x142>(m));  // row_bcast:15
    m = fmaxf(m, dpp_mov<0x143>(m));  // row_bcast:31
    return __int_as_float(__builtin_amdgcn_readlane(__float_as_int(m), 63));
}

__launch_bounds__(64, 1)
__global__ void ctc_loss_kernel(const int* __restrict__ y_true,
                                const float* __restrict__ y_pred,
                                float* __restrict__ out) {
    const int b = blockIdx.x;
    const int lane = threadIdx.x;  // 0..63

    // ---- label metadata ----
    const int yv = y_true[b * L_ + lane];
    const unsigned long long act = __ballot(yv != -1);
    const int len = __popcll(act);        // label length (32..64)
    const int lab = (yv == -1) ? 0 : yv;  // padded like the reference
    const int lab_prev = __shfl_up(lab, 1);
    const bool cs = (lane == 0) ? true : (lab != lab_prev);

    constexpr int U = 8;          // timesteps per chunk
    constexpr int D = 4;          // VGPR ring depth, in chunks
    constexpr int NCH = T_ / U;   // 64 chunks
    constexpr int CHW = U * C_;   // 768 floats per chunk (3 KB)

    // per-lane base for coalesced chunk loads: lane l owns dwords l*4..l*4+3
    // of each 256-dword block; block j of chunk c starts at c*768 + j*256.
    const float* __restrict__ gbase = y_pred + (size_t)b * T_ * C_ + lane * 4;

    __shared__ __align__(16) float smem[2 * CHW];  // 2-slot staging, 6 KB

    // ---- prologue: fill ring with chunks 0..D-1, stage chunk 0 to slot 0 ----
    float4 ring[D][3];
#pragma unroll
    for (int d = 0; d < D; ++d)
#pragma unroll
        for (int j = 0; j < 3; ++j)
            ring[d][j] = *reinterpret_cast<const float4*>(gbase + d * CHW + j * 256);
#pragma unroll
    for (int j = 0; j < 3; ++j)
        *reinterpret_cast<float4*>(&smem[(j * 64 + lane) * 4]) = ring[0][j];

    // ---- DP state: virtual t=-1 init (alpha[-1][0] = 1, scaled by 2^96).
    // One uniform step then yields the reference's alpha0 exactly.
    float a_even = (lane == 0) ? 0x1.0p96f : 0.0f;
    float a_odd = 0.0f;
    float a128 = 0.0f;
    int accum = -96;  // true_alpha = stored * 2^accum

    for (int cc = 0; cc < NCH; cc += D) {
#pragma unroll
        for (int sub = 0; sub < D; ++sub) {
            const int c = cc + sub;

            // (a) prefetch chunk c+D into ring slot sub (fully coalesced)
            if (c + D < NCH) {
#pragma unroll
                for (int j = 0; j < 3; ++j)
                    ring[sub][j] = *reinterpret_cast<const float4*>(
                        gbase + (c + D) * CHW + j * 256);
            }

            // (b) read chunk c's per-step values from LDS slot c&1
            //     (written one full iteration ago -> no same-iter lgkm stall)
            constexpr int U_ = U;
            const int slot = sub & 1;  // c & 1 == sub & 1 (cc % 4 == 0)
            float pl[U_], pb[U_], mpl[U_];
#pragma unroll
            for (int k = 0; k < U_; ++k) {
                pl[k] = smem[slot * CHW + k * C_ + lab] + EPSF;      // lane gather
                pb[k] = smem[slot * CHW + k * C_ + BLANK_] + EPSF;   // broadcast
                mpl[k] = cs ? pl[k] : 0.0f;
            }

            // (c) stage chunk c+1 (already resident in ring) into LDS slot (c+1)&1
            if (c + 1 < NCH) {
                const int nslot = (sub + 1) & 1;
                const int nr = (sub + 1) % D;
#pragma unroll
                for (int j = 0; j < 3; ++j)
                    *reinterpret_cast<float4*>(
                        &smem[nslot * CHW + (j * 64 + lane) * 4]) = ring[nr][j];
            }

            // (d) 8 DP steps (chain: dpp -> fma, ~12 cy)
#pragma unroll
            for (int k = 0; k < U_; ++k) {
                const float po = dpp_mov<0x138>(a_odd);  // wave_shr:1 -> alpha[2*lane-1]
                const float ne = fmaf(po, pb[k], a_even * pb[k]);
                const float no = fmaf(po, mpl[k], (a_odd + a_even) * pl[k]);
                a128 = fmaf(a_odd, pb[k], a128 * pb[k]);  // meaningful on lane 63
                a_even = ne;
                a_odd = no;
            }

            // (e) renorm from the POST-chunk state -> max into (2^95, 2^96]
            const float mv = wave_max(fmaxf(fmaxf(a_even, a_odd), a128));
            const int e = ((__float_as_int(mv) >> 23) & 0xFF) - 126;
            const int kk = 96 - e;
            a_even = ldexpf(a_even, kk);
            a_odd = ldexpf(a_odd, kk);
            a128 = ldexpf(a128, kk);
            accum -= kk;
        }
    }

    // ---- readout: loss = -ln2 * (log2(a[2len] + a[2len-1]) + accum) ----
    const float al = __shfl(a_odd, len - 1);           // state 2len-1
    const float ab = (len < L_) ? __shfl(a_even, len)  // state 2len
                                : __shfl(a128, 63);    // state 128
    if (lane == 0) {
        const float loss = -LN2F * (log2f(ab + al) + (float)accum);
        atomicAdd(out, loss * (1.0f / B_));
    }
}

extern "C" void kernel_launch(void* const* d_in, const int* in_sizes, int n_in,
                              void* d_out, int out_size, void* d_ws, size_t ws_size,
                              hipStream_t stream) {
    const int* y_true = (const int*)d_in[0];
    const float* y_pred = (const float*)d_in[1];
    float* out = (float*)d_out;
    hipMemsetAsync(out, 0, sizeof(float), stream);
    ctc_loss_kernel<<<B_, 64, 0, stream>>>(y_true, y_pred, out);
}

// Round 6
// 182.751 us; speedup vs baseline: 1.0511x; 1.0511x over previous
//
#include <hip/hip_runtime.h>

// CTC loss forward DP (Keras ctc_batch_cost), mean over batch.
// B=512, T=512, C=96 (blank=95), L=64.
//
// R6: producer/consumer wave specialization. Block = 4 waves:
//   wave 0  = consumer: runs the whole serial DP out of LDS, never touches
//             global memory (R4 math: linear space, post-chunk renorm to 2^96,
//             dpp wave_shr:1 neighbor transfer, FMA step).
//   waves 1-3 = producers: producer p owns chunks c with c%3==p. Per turn:
//             ds_write its held chunk (3 KB, 3x ds_write_b128) into slot c&1,
//             then issue 3 coalesced dwordx4 loads for chunk c+3 (in flight
//             for 3 barrier periods ~1200 cy, covering ~900 cy HBM latency).
// Barrier = raw "s_waitcnt lgkmcnt(0); s_barrier" asm with memory clobber:
// does NOT drain vmcnt (producer loads stay in flight across it), and the
// clobber pins loads at their issue site so the scheduler can't sink them
// (R5's failure mode: VGPR ring collapsed, loads sunk to uses, 82us).

#define B_ 512
#define T_ 512
#define C_ 96
#define L_ 64
#define BLANK_ 95
#define EPSF 1e-7f
#define LN2F 0.69314718055994530942f

// Publish own LDS writes (lgkmcnt(0)) + workgroup rendezvous. No vmcnt drain.
#define BARRIER() asm volatile("s_waitcnt lgkmcnt(0)\n\ts_barrier" ::: "memory")

template <int CTRL>
__device__ __forceinline__ float dpp_mov(float x) {
    // bound_ctrl=true: invalid source lanes read 0 (identity for max of
    // non-negative probs; exactly the "state -1 absent" boundary for shr:1).
    return __int_as_float(
        __builtin_amdgcn_update_dpp(0, __float_as_int(x), CTRL, 0xF, 0xF, true));
}

// Full-wave max (64 lanes), all-VALU; full reduction lands in lane 63.
__device__ __forceinline__ float wave_max(float m) {
    m = fmaxf(m, dpp_mov<0x111>(m));  // row_shr:1
    m = fmaxf(m, dpp_mov<0x112>(m));  // row_shr:2
    m = fmaxf(m, dpp_mov<0x114>(m));  // row_shr:4
    m = fmaxf(m, dpp_mov<0x118>(m));  // row_shr:8
    m = fmaxf(m, dpp_mov<0x142>(m));  // row_bcast:15
    m = fmaxf(m, dpp_mov<0x143>(m));  // row_bcast:31
    return __int_as_float(__builtin_amdgcn_readlane(__float_as_int(m), 63));
}

__launch_bounds__(256, 1)
__global__ void ctc_loss_kernel(const int* __restrict__ y_true,
                                const float* __restrict__ y_pred,
                                float* __restrict__ out) {
    const int b = blockIdx.x;
    const int tid = threadIdx.x;
    const int wid = tid >> 6;    // 0 = consumer, 1..3 = producers
    const int lane = tid & 63;

    constexpr int U = 8;          // timesteps per chunk
    constexpr int NCH = T_ / U;   // 64 chunks
    constexpr int CHW = U * C_;   // 768 floats per chunk (3 KB)

    __shared__ __align__(16) float smem[2 * CHW];  // 2-slot staging (6 KB)

    // coalesced chunk addressing: lane l owns dwords 4l..4l+3 of each
    // 256-dword block; block j of chunk c starts at c*CHW + j*256.
    const float* __restrict__ gb = y_pred + (size_t)b * T_ * C_ + lane * 4;

    // ---- consumer state ----
    int len = 0, lab = 0;
    bool cs = false;
    float a_even = 0.0f, a_odd = 0.0f, a128 = 0.0f;
    int accum = -96;  // true_alpha = stored * 2^accum
    // ---- producer state ----
    float4 rg[3];

    if (wid == 0) {
        // Consumer setup. Virtual t=-1 init: alpha[-1][0] = 1 (scaled 2^96);
        // one uniform DP step then yields the reference alpha0 exactly.
        const int yv = y_true[b * L_ + lane];
        const unsigned long long act = __ballot(yv != -1);
        len = __popcll(act);              // label length (32..64)
        lab = (yv == -1) ? 0 : yv;        // padded like the reference
        const int lab_prev = __shfl_up(lab, 1);
        cs = (lane == 0) ? true : (lab != lab_prev);
        a_even = (lane == 0) ? 0x1.0p96f : 0.0f;
    } else {
        // Producer p owns chunks {c : c%3 == p}; chunk c is ds_written at
        // iteration c-1 (chunk 0 in the prologue) and read at iteration c.
        const int p = wid - 1;
        const int c0 = (p == 0) ? 0 : p;  // first held chunk
#pragma unroll
        for (int j = 0; j < 3; ++j)
            rg[j] = *reinterpret_cast<const float4*>(gb + c0 * CHW + j * 256);
        if (p == 0) {
            // stage chunk 0 into slot 0 now; then pre-load chunk 3
#pragma unroll
            for (int j = 0; j < 3; ++j)
                *reinterpret_cast<float4*>(&smem[(j * 64 + lane) * 4]) = rg[j];
#pragma unroll
            for (int j = 0; j < 3; ++j)
                rg[j] = *reinterpret_cast<const float4*>(gb + 3 * CHW + j * 256);
        }
    }

    for (int i = 0; i < NCH; ++i) {
        BARRIER();  // publishes last iteration's ds_writes; no vmcnt drain
        if (wid == 0) {
            // ---- consumer: chunk i from slot i&1 ----
            const float* sl = smem + (i & 1) * CHW;
            float pl[U], pb[U], mpl[U];
#pragma unroll
            for (int k = 0; k < U; ++k) {
                pl[k] = sl[k * C_ + lab] + EPSF;     // per-lane LDS gather
                pb[k] = sl[k * C_ + BLANK_] + EPSF;  // uniform broadcast
                mpl[k] = cs ? pl[k] : 0.0f;
            }
#pragma unroll
            for (int k = 0; k < U; ++k) {
                const float po = dpp_mov<0x138>(a_odd);  // alpha[2*lane-1]
                const float ne = fmaf(po, pb[k], a_even * pb[k]);
                const float no = fmaf(po, mpl[k], (a_odd + a_even) * pl[k]);
                a128 = fmaf(a_odd, pb[k], a128 * pb[k]);  // lane 63 meaningful
                a_even = ne;
                a_odd = no;
            }
            // post-chunk renorm: wave max -> (2^95, 2^96]
            const float mv = wave_max(fmaxf(fmaxf(a_even, a_odd), a128));
            const int e = ((__float_as_int(mv) >> 23) & 0xFF) - 126;
            const int kk = 96 - e;
            a_even = ldexpf(a_even, kk);
            a_odd = ldexpf(a_odd, kk);
            a128 = ldexpf(a128, kk);
            accum -= kk;
        } else {
            // ---- producer turn: write chunk i+1, load chunk i+4 ----
            const int p = wid - 1;
            const int cw = i + 1;
            if (cw < NCH && (cw % 3) == p) {
                float* dst = smem + (cw & 1) * CHW;
#pragma unroll
                for (int j = 0; j < 3; ++j)  // vmcnt wait auto-inserted here
                    *reinterpret_cast<float4*>(&dst[(j * 64 + lane) * 4]) = rg[j];
                const int nc = cw + 3;
                if (nc < NCH) {
#pragma unroll
                    for (int j = 0; j < 3; ++j)
                        rg[j] = *reinterpret_cast<const float4*>(
                            gb + nc * CHW + j * 256);
                }
            }
        }
    }

    // ---- readout: loss = -ln2 * (log2(a[2len] + a[2len-1]) + accum) ----
    if (wid == 0) {
        const float al = __shfl(a_odd, len - 1);           // state 2len-1
        const float ab = (len < L_) ? __shfl(a_even, len)  // state 2len
                                    : __shfl(a128, 63);    // state 128
        if (lane == 0) {
            const float loss = -LN2F * (log2f(ab + al) + (float)accum);
            atomicAdd(out, loss * (1.0f / B_));
        }
    }
}

extern "C" void kernel_launch(void* const* d_in, const int* in_sizes, int n_in,
                              void* d_out, int out_size, void* d_ws, size_t ws_size,
                              hipStream_t stream) {
    const int* y_true = (const int*)d_in[0];
    const float* y_pred = (const float*)d_in[1];
    float* out = (float*)d_out;
    hipMemsetAsync(out, 0, sizeof(float), stream);
    ctc_loss_kernel<<<B_, 256, 0, stream>>>(y_true, y_pred, out);
}

// Round 7
// 176.554 us; speedup vs baseline: 1.0880x; 1.0351x over previous
//
#include <hip/hip_runtime.h>

// CTC loss forward DP (Keras ctc_batch_cost), mean over batch.
// B=512, T=512, C=96 (blank=95), L=64.
//
// R7: producer/consumer with a software-pipelined consumer.
//   wave 0  = consumer: steps chunk i out of REGISTERS (read during iter i-1),
//             while issuing LDS reads for chunk i+1 (ping-pong reg sets
//             pl[2][8]/pb[2][8] -> compiler can't interleave read->use, which
//             was R6's 3150 cy/iter limiter: VGPR=20 proved per-step LDS
//             round-trips).
//   waves 1-3 = producers: producer p owns chunks c%3==p; writes chunk i+2
//             during iter i into a 4-slot LDS ring (12 KB); then loads chunk
//             i+5 (3 barrier periods in flight).
// Barrier = "s_waitcnt lgkmcnt(0); s_barrier" (no vmcnt drain: producer
// global loads stay in flight across it). DP math identical to R4-R6:
// linear space, post-chunk renorm to 2^96, dpp wave_shr:1, FMA step.

#define B_ 512
#define T_ 512
#define C_ 96
#define L_ 64
#define BLANK_ 95
#define EPSF 1e-7f
#define LN2F 0.69314718055994530942f

// Publish own LDS writes + workgroup rendezvous. No vmcnt drain.
#define BARRIER() asm volatile("s_waitcnt lgkmcnt(0)\n\ts_barrier" ::: "memory")
// Scheduling fence: memory ops cannot cross (loads can't sink below it).
#define SCHED_FENCE() asm volatile("" ::: "memory")

template <int CTRL>
__device__ __forceinline__ float dpp_mov(float x) {
    // bound_ctrl=true: invalid source lanes read 0 (identity for max of
    // non-negative probs; exactly the "state -1 absent" boundary for shr:1).
    return __int_as_float(
        __builtin_amdgcn_update_dpp(0, __float_as_int(x), CTRL, 0xF, 0xF, true));
}

// Full-wave max (64 lanes), all-VALU; full reduction lands in lane 63.
__device__ __forceinline__ float wave_max(float m) {
    m = fmaxf(m, dpp_mov<0x111>(m));  // row_shr:1
    m = fmaxf(m, dpp_mov<0x112>(m));  // row_shr:2
    m = fmaxf(m, dpp_mov<0x114>(m));  // row_shr:4
    m = fmaxf(m, dpp_mov<0x118>(m));  // row_shr:8
    m = fmaxf(m, dpp_mov<0x142>(m));  // row_bcast:15
    m = fmaxf(m, dpp_mov<0x143>(m));  // row_bcast:31
    return __int_as_float(__builtin_amdgcn_readlane(__float_as_int(m), 63));
}

__launch_bounds__(256, 1)
__global__ void ctc_loss_kernel(const int* __restrict__ y_true,
                                const float* __restrict__ y_pred,
                                float* __restrict__ out) {
    const int b = blockIdx.x;
    const int tid = threadIdx.x;
    const int wid = tid >> 6;    // 0 = consumer, 1..3 = producers
    const int lane = tid & 63;

    constexpr int U = 8;          // timesteps per chunk
    constexpr int NCH = T_ / U;   // 64 chunks
    constexpr int CHW = U * C_;   // 768 floats per chunk (3 KB)

    __shared__ __align__(16) float smem[4 * CHW];  // 4-slot ring (12 KB)

    // coalesced chunk addressing: lane l owns dwords 4l..4l+3 of each
    // 256-dword block; block j of chunk c starts at c*CHW + j*256.
    const float* __restrict__ gb = y_pred + (size_t)b * T_ * C_ + lane * 4;

    if (wid == 0) {
        // ================= consumer =================
        const int yv = y_true[b * L_ + lane];
        const unsigned long long act = __ballot(yv != -1);
        const int len = __popcll(act);        // label length (32..64)
        const int lab = (yv == -1) ? 0 : yv;  // padded like the reference
        const int lab_prev = __shfl_up(lab, 1);
        const bool cs = (lane == 0) ? true : (lab != lab_prev);

        // Virtual t=-1 init: alpha[-1][0] = 1 (scaled 2^96); one uniform DP
        // step then yields the reference alpha0 exactly.
        float a_even = (lane == 0) ? 0x1.0p96f : 0.0f;
        float a_odd = 0.0f, a128 = 0.0f;
        int accum = -96;  // true_alpha = stored * 2^accum

        const float* sl_lab = smem + lab;     // per-lane label base
        const float* sl_blk = smem + BLANK_;  // uniform blank base

        float pl[2][U], pb[2][U];  // ping-pong: set (i&1) holds chunk i

        BARRIER();  // barrier #0: publishes chunks 0 (slot 0) and 1 (slot 1)

        // pre-read chunk 0 into set 0
#pragma unroll
        for (int k = 0; k < U; ++k) {
            pl[0][k] = sl_lab[k * C_];
            pb[0][k] = sl_blk[k * C_];
        }
        SCHED_FENCE();

        for (int ii = 0; ii < NCH / 4; ++ii) {
#pragma unroll
            for (int sub = 0; sub < 4; ++sub) {
                const int cur = sub & 1, nxt = cur ^ 1;
                const int nslot = (sub + 1) & 3;  // slot of chunk i+1

                // (a) issue LDS reads for chunk i+1 (published by the last
                //     barrier; at i=63 this reads stale slot 0 -> never used)
#pragma unroll
                for (int k = 0; k < U; ++k) {
                    pl[nxt][k] = sl_lab[nslot * CHW + k * C_];
                    pb[nxt][k] = sl_blk[nslot * CHW + k * C_];
                }
                SCHED_FENCE();  // reads pinned above the step loop

                // (b) 8 DP steps on registers of chunk i
#pragma unroll
                for (int k = 0; k < U; ++k) {
                    const float plk = pl[cur][k] + EPSF;
                    const float pbk = pb[cur][k] + EPSF;
                    const float po = dpp_mov<0x138>(a_odd);  // alpha[2*lane-1]
                    const float ne = fmaf(po, pbk, a_even * pbk);
                    const float no =
                        fmaf(po, cs ? plk : 0.0f, (a_odd + a_even) * plk);
                    a128 = fmaf(a_odd, pbk, a128 * pbk);  // lane 63 meaningful
                    a_even = ne;
                    a_odd = no;
                }

                // (c) post-chunk renorm: wave max -> (2^95, 2^96]
                const float mv = wave_max(fmaxf(fmaxf(a_even, a_odd), a128));
                const int e = ((__float_as_int(mv) >> 23) & 0xFF) - 126;
                const int kk = 96 - e;
                a_even = ldexpf(a_even, kk);
                a_odd = ldexpf(a_odd, kk);
                a128 = ldexpf(a128, kk);
                accum -= kk;

                BARRIER();
            }
        }

        // readout: loss = -ln2 * (log2(a[2len] + a[2len-1]) + accum)
        const float al = __shfl(a_odd, len - 1);           // state 2len-1
        const float ab = (len < L_) ? __shfl(a_even, len)  // state 2len
                                    : __shfl(a128, 63);    // state 128
        if (lane == 0) {
            const float loss = -LN2F * (log2f(ab + al) + (float)accum);
            atomicAdd(out, loss * (1.0f / B_));
        }
    } else {
        // ================= producers =================
        const int p = wid - 1;            // 0..2, owns chunks c%3 == p
        const int c0 = (p == 0) ? 0 : p;  // first owned chunk
        float4 rg[3];
#pragma unroll
        for (int j = 0; j < 3; ++j)
            rg[j] = *reinterpret_cast<const float4*>(gb + c0 * CHW + j * 256);
        if (p <= 1) {
            // stage chunk 0/1 now (slots 0/1), then pre-load chunk c0+3
            float* dst = smem + c0 * CHW;
#pragma unroll
            for (int j = 0; j < 3; ++j)
                *reinterpret_cast<float4*>(&dst[(j * 64 + lane) * 4]) = rg[j];
#pragma unroll
            for (int j = 0; j < 3; ++j)
                rg[j] = *reinterpret_cast<const float4*>(gb + (c0 + 3) * CHW +
                                                         j * 256);
        }
        BARRIER();  // barrier #0

        for (int ii = 0; ii < NCH / 4; ++ii) {
#pragma unroll
            for (int sub = 0; sub < 4; ++sub) {
                const int i = ii * 4 + sub;
                const int cw = i + 2;  // chunk written this iteration
                if (cw < NCH && cw % 3 == p) {
                    float* dst = smem + (cw & 3) * CHW;
#pragma unroll
                    for (int j = 0; j < 3; ++j)  // vmcnt wait auto-inserted
                        *reinterpret_cast<float4*>(&dst[(j * 64 + lane) * 4]) =
                            rg[j];
                    const int nc = cw + 3;  // next owned chunk: 3 periods in flight
                    if (nc < NCH) {
#pragma unroll
                        for (int j = 0; j < 3; ++j)
                            rg[j] = *reinterpret_cast<const float4*>(
                                gb + nc * CHW + j * 256);
                    }
                }
                BARRIER();
            }
        }
    }
}

extern "C" void kernel_launch(void* const* d_in, const int* in_sizes, int n_in,
                              void* d_out, int out_size, void* d_ws, size_t ws_size,
                              hipStream_t stream) {
    const int* y_true = (const int*)d_in[0];
    const float* y_pred = (const float*)d_in[1];
    float* out = (float*)d_out;
    hipMemsetAsync(out, 0, sizeof(float), stream);
    ctc_loss_kernel<<<B_, 256, 0, stream>>>(y_true, y_pred, out);
}